// Round 1
// baseline (85.274 us; speedup 1.0000x reference)
//
#include <hip/hip_runtime.h>
#include <hip/hip_bf16.h>
#include <cstddef>

typedef __bf16 bf16x8 __attribute__((ext_vector_type(8)));
typedef float  f32x4  __attribute__((ext_vector_type(4)));

#define NB 16
#define NL 512
#define NH 768
#define NROWS (NB*NL)      // 8192
#define NSEQ 128           // seq columns
#define NPAD 192           // padded GEMM N: 128 seq + 24 bias + 40 zero
#define NHEADS 12
#define NBIAS 24           // 2*HEADS
#define DHEAD 64
#define BIGNEG 1000000000000.0f

// workspace byte offsets
#define OFF_PWT   0            // bf16 [192][768]  = 294912 B
#define OFF_B2    294912       // f32 [24]         (pad to 128)
#define OFF_QRT   295040       // f32 [16][64][512] = 2 MB (d-major roped q)
#define OFF_KRT   2392192      // f32 [16][64][512] = 2 MB
#define OFF_BIAS  4489344      // f32 [8192][24]   = 786432 B
// total 5275776 B

// Build B^T in bf16: rows 0..127 = pW^T, rows 128..151 = (pW@qW)^T, rest 0.
__global__ void prep_wt(const float* __restrict__ pW, const float* __restrict__ qW,
                        __bf16* __restrict__ pWT) {
  int idx = blockIdx.x * 256 + threadIdx.x;
  if (idx >= NPAD * NH) return;
  int n = idx / NH, k = idx % NH;
  float v = 0.f;
  if (n < NSEQ) {
    v = pW[k * NSEQ + n];
  } else if (n < NSEQ + NBIAS) {
    int c = n - NSEQ;
    float a = 0.f;
    for (int j = 0; j < NSEQ; ++j) a += pW[k * NSEQ + j] * qW[j * NBIAS + c];
    v = a;
  }
  pWT[idx] = (__bf16)v;
}

__global__ void prep_b2(const float* __restrict__ pb, const float* __restrict__ qW,
                        const float* __restrict__ qb, float* __restrict__ b2) {
  int c = threadIdx.x;
  if (c < NBIAS) {
    float a = qb[c];
    for (int j = 0; j < NSEQ; ++j) a += pb[j] * qW[j * NBIAS + c];
    b2[c] = a;
  }
}

// Fused GEMM (hidden @ [pW | pW@qW]) + pb/b2 + RoPE epilogue.
// BM=16 rows/block, 512 blocks, 4 waves; wave w owns n-fragments {3w,3w+1,3w+2}.
// No LDS: A-frags direct from global (f32->bf16 cvt), B-frags from L2-hot pWT.
__launch_bounds__(256)
__global__ void gemm_rope(const float* __restrict__ hidden, const __bf16* __restrict__ pWT,
                          const float* __restrict__ pb, const float* __restrict__ b2,
                          float* __restrict__ qrT, float* __restrict__ krT,
                          float* __restrict__ biasw) {
  int m0 = blockIdx.x * 16;
  int tid = threadIdx.x;
  int wave = tid >> 6, lane = tid & 63;
  int lrow = lane & 15, lk = (lane >> 4) * 8;   // A/B frag: row=lane&15, k-chunk=(lane>>4)*8
  f32x4 acc0 = {0,0,0,0}, acc1 = {0,0,0,0}, acc2 = {0,0,0,0};
  const float*  arow = hidden + (size_t)(m0 + lrow) * NH;
  const __bf16* bp0  = pWT + (size_t)((wave*3+0)*16 + lrow) * NH;
  const __bf16* bp1  = pWT + (size_t)((wave*3+1)*16 + lrow) * NH;
  const __bf16* bp2  = pWT + (size_t)((wave*3+2)*16 + lrow) * NH;
  for (int k0 = 0; k0 < NH; k0 += 32) {
    f32x4 h0 = *(const f32x4*)(arow + k0 + lk);
    f32x4 h1 = *(const f32x4*)(arow + k0 + lk + 4);
    bf16x8 af;
    af[0]=(__bf16)h0[0]; af[1]=(__bf16)h0[1]; af[2]=(__bf16)h0[2]; af[3]=(__bf16)h0[3];
    af[4]=(__bf16)h1[0]; af[5]=(__bf16)h1[1]; af[6]=(__bf16)h1[2]; af[7]=(__bf16)h1[3];
    bf16x8 b0 = *(const bf16x8*)(bp0 + k0 + lk);
    bf16x8 b1 = *(const bf16x8*)(bp1 + k0 + lk);
    bf16x8 b2f = *(const bf16x8*)(bp2 + k0 + lk);
    acc0 = __builtin_amdgcn_mfma_f32_16x16x32_bf16(af, b0, acc0, 0, 0, 0);
    acc1 = __builtin_amdgcn_mfma_f32_16x16x32_bf16(af, b1, acc1, 0, 0, 0);
    acc2 = __builtin_amdgcn_mfma_f32_16x16x32_bf16(af, b2f, acc2, 0, 0, 0);
  }
  // C/D layout: col = lane&15, row = (lane>>4)*4 + reg
  int rowoff = (lane >> 4) * 4;
  #pragma unroll
  for (int f = 0; f < 3; ++f) {
    f32x4 a = (f == 0) ? acc0 : (f == 1) ? acc1 : acc2;
    int col = (wave*3 + f) * 16 + lrow;
    bool isseq = (col < NSEQ);                       // frag-uniform (16-col frags)
    float addc = isseq ? pb[col] : ((col < NSEQ + NBIAS) ? b2[col - NSEQ] : 0.f);
    #pragma unroll
    for (int r = 0; r < 4; ++r) {
      int rg = m0 + rowoff + r;                      // global row in [0,8192)
      float val = a[r] + addc;
      if (isseq) {
        // RoPE: pair columns (2p,2p+1) live in adjacent lanes
        float pv = __shfl_xor(val, 1, 64);
        int d = col & 63;
        float x2 = (d & 1) ? pv : -pv;
        int p = d >> 1;
        float ang = (float)(rg & (NL - 1)) * __expf((float)p * (-9.210340371976184f / 32.0f));
        float sn = __sinf(ang), cs = __cosf(ang);
        float res = val * cs + x2 * sn;
        int bi = rg >> 9, l = rg & (NL - 1);
        float* dst = (col < DHEAD) ? qrT : krT;
        dst[(size_t)(bi * DHEAD + d) * NL + l] = res;   // d-major for kernel 2
      } else if (col < NSEQ + NBIAS) {
        biasw[(size_t)rg * NBIAS + (col - NSEQ)] = val;
      }
    }
  }
}

// Per block: 64(m) x 64(n) tile for one batch, all 12 heads.
// q/k staged d-major into stride-68 LDS (float4 reads, 2-way aliasing = free).
__launch_bounds__(256)
__global__ void logits_kernel(const float* __restrict__ qrT, const float* __restrict__ krT,
                              const float* __restrict__ biasw, const int* __restrict__ amask,
                              float* __restrict__ out) {
  int bx = blockIdx.x, by = blockIdx.y, bz = blockIdx.z;
  int tid = threadIdx.x;
  __shared__ float qs[64][68];
  __shared__ float ks[64][68];
  __shared__ float b0s[64][13];
  __shared__ float b1s[64][13];
  __shared__ float padf[64];
  int m0 = by * 64, n0 = bx * 64;
  #pragma unroll
  for (int it = 0; it < 4; ++it) {
    int flat = it * 1024 + tid * 4;
    int d = flat >> 6, c4 = flat & 63;
    *(f32x4*)&qs[d][c4] = *(const f32x4*)(qrT + (size_t)(bz * DHEAD + d) * NL + m0 + c4);
    *(f32x4*)&ks[d][c4] = *(const f32x4*)(krT + (size_t)(bz * DHEAD + d) * NL + n0 + c4);
  }
  for (int idx = tid; idx < 64 * NHEADS; idx += 256) {
    int r = idx / NHEADS, h = idx - r * NHEADS;
    b0s[r][h] = biasw[(size_t)(bz * NL + m0 + r) * NBIAS + 2 * h];
    b1s[r][h] = biasw[(size_t)(bz * NL + n0 + r) * NBIAS + 2 * h + 1];
  }
  if (tid < 64) padf[tid] = (float)amask[bz * NL + n0 + tid];
  __syncthreads();

  int tx = tid & 15, ty = tid >> 4;
  float acc[4][4] = {};
  #pragma unroll 8
  for (int d = 0; d < 64; ++d) {
    f32x4 qv = *(const f32x4*)&qs[d][ty * 4];
    f32x4 kv = *(const f32x4*)&ks[d][tx * 4];
    #pragma unroll
    for (int i = 0; i < 4; ++i)
      #pragma unroll
      for (int j = 0; j < 4; ++j)
        acc[i][j] += qv[i] * kv[j];
  }

  #pragma unroll
  for (int i = 0; i < 4; ++i) {
    int ml = ty * 4 + i;
    int mg = m0 + ml;
    #pragma unroll
    for (int h = 0; h < NHEADS; ++h) {
      float b0 = b0s[ml][h];
      f32x4 o;
      #pragma unroll
      for (int j = 0; j < 4; ++j) {
        int nl = tx * 4 + j;
        float v = acc[i][j] * 0.125f + b0 + b1s[nl][h];
        float pd = padf[nl];
        v = v * pd - (1.f - pd) * BIGNEG;   // exact when pad==1 (no cancellation)
        if (mg > n0 + nl) v -= BIGNEG;      // tril(-1) causal mask
        o[j] = v;
      }
      size_t oaddr = ((size_t)((bz * NHEADS + h) * NL + mg)) * NL + n0 + tx * 4;
      *(f32x4*)(out + oaddr) = o;
    }
  }
}

extern "C" void kernel_launch(void* const* d_in, const int* in_sizes, int n_in,
                              void* d_out, int out_size, void* d_ws, size_t ws_size,
                              hipStream_t stream) {
  const float* hidden = (const float*)d_in[0];
  const int*   amask  = (const int*)d_in[1];
  const float* pW     = (const float*)d_in[2];
  const float* pb     = (const float*)d_in[3];
  const float* qW     = (const float*)d_in[4];
  const float* qb     = (const float*)d_in[5];
  float* out = (float*)d_out;
  char*  ws  = (char*)d_ws;
  __bf16* pWT  = (__bf16*)(ws + OFF_PWT);
  float*  b2   = (float*)(ws + OFF_B2);
  float*  qrT  = (float*)(ws + OFF_QRT);
  float*  krT  = (float*)(ws + OFF_KRT);
  float*  bias = (float*)(ws + OFF_BIAS);

  prep_wt<<<(NPAD * NH + 255) / 256, 256, 0, stream>>>(pW, qW, pWT);
  prep_b2<<<1, 64, 0, stream>>>(pb, qW, qb, b2);
  gemm_rope<<<NROWS / 16, 256, 0, stream>>>(hidden, pWT, pb, b2, qrT, krT, bias);
  logits_kernel<<<dim3(NL / 64, NL / 64, NB), 256, 0, stream>>>(qrT, krT, bias, amask, out);
}

// Round 2
// 83.938 us; speedup vs baseline: 1.0159x; 1.0159x over previous
//
#include <hip/hip_runtime.h>
#include <hip/hip_bf16.h>
#include <cstddef>

typedef __bf16 bf16x8 __attribute__((ext_vector_type(8)));
typedef float  f32x4  __attribute__((ext_vector_type(4)));
typedef float  f32x16 __attribute__((ext_vector_type(16)));

#define NB 16
#define NL 512
#define NH 768
#define NROWS (NB*NL)      // 8192
#define NSEQ 128           // seq columns
#define NPAD 192           // padded GEMM N: 128 seq + 24 bias + 40 zero
#define NHEADS 12
#define NBIAS 24           // 2*HEADS
#define DHEAD 64
#define BIGNEG 1000000000000.0f

// workspace byte offsets
#define OFF_PWT   0            // bf16 [192][768]   = 294912 B
#define OFF_B2    294912       // f32 [24] (pad 128)
#define OFF_QRB   295040       // bf16 [16][512][64] = 1 MB  (roped q, row-major [l][d])
#define OFF_KRB   1343616      // bf16 [16][512][64] = 1 MB
#define OFF_BIAS  2392192      // f32 [8192][24]     = 786432 B
// total 3178624 B

// Build B^T in bf16: rows 0..127 = pW^T, rows 128..151 = (pW@qW)^T, rest 0.
// Extra block (576) computes b2 = pb@qW + qb.
__global__ void prep_wt(const float* __restrict__ pW, const float* __restrict__ qW,
                        const float* __restrict__ pb, const float* __restrict__ qb,
                        __bf16* __restrict__ pWT, float* __restrict__ b2) {
  if (blockIdx.x == 576) {
    int c = threadIdx.x;
    if (c < NBIAS) {
      float a = qb[c];
      for (int j = 0; j < NSEQ; ++j) a += pb[j] * qW[j * NBIAS + c];
      b2[c] = a;
    }
    return;
  }
  int idx = blockIdx.x * 256 + threadIdx.x;   // covers NPAD*NH exactly
  int n = idx / NH, k = idx % NH;
  float v = 0.f;
  if (n < NSEQ) {
    v = pW[k * NSEQ + n];
  } else if (n < NSEQ + NBIAS) {
    int c = n - NSEQ;
    float a = 0.f;
    for (int j = 0; j < NSEQ; ++j) a += pW[k * NSEQ + j] * qW[j * NBIAS + c];
    v = a;
  }
  pWT[idx] = (__bf16)v;
}

// Fused GEMM (hidden @ [pW | pW@qW]) + pb/b2 + RoPE epilogue.
// BM=16 rows/block, 512 blocks, 4 waves; wave w owns n-fragments {3w,3w+1,3w+2}.
// Epilogue writes roped q/k as bf16 [b][l][64] for the MFMA logits kernel.
__launch_bounds__(256)
__global__ void gemm_rope(const float* __restrict__ hidden, const __bf16* __restrict__ pWT,
                          const float* __restrict__ pb, const float* __restrict__ b2,
                          __bf16* __restrict__ qrB, __bf16* __restrict__ krB,
                          float* __restrict__ biasw) {
  int m0 = blockIdx.x * 16;
  int tid = threadIdx.x;
  int wave = tid >> 6, lane = tid & 63;
  int lrow = lane & 15, lk = (lane >> 4) * 8;   // A/B frag: row=lane&15, k-chunk=(lane>>4)*8
  f32x4 acc0 = {0,0,0,0}, acc1 = {0,0,0,0}, acc2 = {0,0,0,0};
  const float*  arow = hidden + (size_t)(m0 + lrow) * NH;
  const __bf16* bp0  = pWT + (size_t)((wave*3+0)*16 + lrow) * NH;
  const __bf16* bp1  = pWT + (size_t)((wave*3+1)*16 + lrow) * NH;
  const __bf16* bp2  = pWT + (size_t)((wave*3+2)*16 + lrow) * NH;
  for (int k0 = 0; k0 < NH; k0 += 32) {
    f32x4 h0 = *(const f32x4*)(arow + k0 + lk);
    f32x4 h1 = *(const f32x4*)(arow + k0 + lk + 4);
    bf16x8 af;
    af[0]=(__bf16)h0[0]; af[1]=(__bf16)h0[1]; af[2]=(__bf16)h0[2]; af[3]=(__bf16)h0[3];
    af[4]=(__bf16)h1[0]; af[5]=(__bf16)h1[1]; af[6]=(__bf16)h1[2]; af[7]=(__bf16)h1[3];
    bf16x8 b0 = *(const bf16x8*)(bp0 + k0 + lk);
    bf16x8 b1 = *(const bf16x8*)(bp1 + k0 + lk);
    bf16x8 b2f = *(const bf16x8*)(bp2 + k0 + lk);
    acc0 = __builtin_amdgcn_mfma_f32_16x16x32_bf16(af, b0, acc0, 0, 0, 0);
    acc1 = __builtin_amdgcn_mfma_f32_16x16x32_bf16(af, b1, acc1, 0, 0, 0);
    acc2 = __builtin_amdgcn_mfma_f32_16x16x32_bf16(af, b2f, acc2, 0, 0, 0);
  }
  // C/D layout: col = lane&15, row = (lane>>4)*4 + reg
  int rowoff = (lane >> 4) * 4;
  #pragma unroll
  for (int f = 0; f < 3; ++f) {
    f32x4 a = (f == 0) ? acc0 : (f == 1) ? acc1 : acc2;
    int col = (wave*3 + f) * 16 + lrow;
    bool isseq = (col < NSEQ);                       // frag-uniform (16-col frags)
    float addc = isseq ? pb[col] : ((col < NSEQ + NBIAS) ? b2[col - NSEQ] : 0.f);
    #pragma unroll
    for (int r = 0; r < 4; ++r) {
      int rg = m0 + rowoff + r;                      // global row in [0,8192)
      float val = a[r] + addc;
      if (isseq) {
        // RoPE: pair columns (2p,2p+1) live in adjacent lanes
        float pv = __shfl_xor(val, 1, 64);
        int d = col & 63;
        float x2 = (d & 1) ? pv : -pv;
        int p = d >> 1;
        float ang = (float)(rg & (NL - 1)) * __expf((float)p * (-9.210340371976184f / 32.0f));
        float sn = __sinf(ang), cs = __cosf(ang);
        float res = val * cs + x2 * sn;
        int bi = rg >> 9, l = rg & (NL - 1);
        __bf16* dst = (col < DHEAD) ? qrB : krB;
        dst[((size_t)bi * NL + l) * DHEAD + d] = (__bf16)res;  // [b][l][d] bf16
      } else if (col < NSEQ + NBIAS) {
        biasw[(size_t)rg * NBIAS + (col - NSEQ)] = val;
      }
    }
  }
}

// Per block: 64(m) x 64(n) tile, one batch, all 12 heads. QK^T via bf16 MFMA,
// frags straight from L2-resident qrB/krB (no q/k LDS). Write-bound by design.
__launch_bounds__(256)
__global__ void logits_kernel(const __bf16* __restrict__ qr, const __bf16* __restrict__ kr,
                              const float* __restrict__ biasw, const int* __restrict__ amask,
                              float* __restrict__ out) {
  int bx = blockIdx.x, by = blockIdx.y, bz = blockIdx.z;
  int tid = threadIdx.x;
  int m0 = by * 64, n0 = bx * 64;
  __shared__ float b0s[64][13];
  __shared__ float b1s[64][13];
  __shared__ float padf[64];
  for (int idx = tid; idx < 64 * NHEADS; idx += 256) {
    int r = idx / NHEADS, h = idx - r * NHEADS;
    b0s[r][h] = biasw[(size_t)(bz * NL + m0 + r) * NBIAS + 2 * h];
    b1s[r][h] = biasw[(size_t)(bz * NL + n0 + r) * NBIAS + 2 * h + 1];
  }
  if (tid < 64) padf[tid] = (float)amask[bz * NL + n0 + tid];
  __syncthreads();

  int wave = tid >> 6, lane = tid & 63;
  int wm = wave >> 1, wn = wave & 1;            // 2x2 wave grid of 32x32 tiles
  int lr = lane & 31, koff = (lane >> 5) * 8;
  const __bf16* qb = qr + ((size_t)(bz * NL + m0 + wm * 32 + lr)) * DHEAD + koff;
  const __bf16* kb = kr + ((size_t)(bz * NL + n0 + wn * 32 + lr)) * DHEAD + koff;
  f32x16 acc = {};
  #pragma unroll
  for (int kk = 0; kk < 4; ++kk) {
    bf16x8 a = *(const bf16x8*)(qb + kk * 16);
    bf16x8 b = *(const bf16x8*)(kb + kk * 16);
    acc = __builtin_amdgcn_mfma_f32_32x32x16_bf16(a, b, acc, 0, 0, 0);
  }
  int nl = wn * 32 + lr;                        // this lane's n within the 64-tile
  float pd = padf[nl];
  float padsub = (1.f - pd) * BIGNEG;
  float b1v[12];
  #pragma unroll
  for (int h = 0; h < NHEADS; ++h) b1v[h] = b1s[nl][h];
  int rb = 4 * (lane >> 5) + wm * 32;
  #pragma unroll
  for (int r = 0; r < 16; ++r) {
    int ml = (r & 3) + 8 * (r >> 2) + rb;       // C/D row mapping
    int mg = m0 + ml;
    float sub = padsub + ((mg > n0 + nl) ? BIGNEG : 0.f);  // causal tril(-1)
    float base = acc[r] * 0.125f;
    #pragma unroll
    for (int h = 0; h < NHEADS; ++h) {
      float v = base + b0s[ml][h] + b1v[h];
      v = v * pd - sub;
      __builtin_nontemporal_store(
          v, out + ((size_t)((bz * NHEADS + h) * NL) + mg) * NL + n0 + nl);
    }
  }
}

extern "C" void kernel_launch(void* const* d_in, const int* in_sizes, int n_in,
                              void* d_out, int out_size, void* d_ws, size_t ws_size,
                              hipStream_t stream) {
  const float* hidden = (const float*)d_in[0];
  const int*   amask  = (const int*)d_in[1];
  const float* pW     = (const float*)d_in[2];
  const float* pb     = (const float*)d_in[3];
  const float* qW     = (const float*)d_in[4];
  const float* qb     = (const float*)d_in[5];
  float* out = (float*)d_out;
  char*  ws  = (char*)d_ws;
  __bf16* pWT  = (__bf16*)(ws + OFF_PWT);
  float*  b2   = (float*)(ws + OFF_B2);
  __bf16* qrB  = (__bf16*)(ws + OFF_QRB);
  __bf16* krB  = (__bf16*)(ws + OFF_KRB);
  float*  bias = (float*)(ws + OFF_BIAS);

  prep_wt<<<577, 256, 0, stream>>>(pW, qW, pb, qb, pWT, b2);
  gemm_rope<<<NROWS / 16, 256, 0, stream>>>(hidden, pWT, pb, b2, qrB, krB, bias);
  logits_kernel<<<dim3(NL / 64, NL / 64, NB), 256, 0, stream>>>(qrB, krB, bias, amask, out);
}